// Round 10
// baseline (180.812 us; speedup 1.0000x reference)
//
#include <hip/hip_runtime.h>

// B=4, H=W=64, D=256, N=8, K=V=32, H2=W2=32, HW=4096, M=1024 pooled/batch.

typedef _Float16 f16x8 __attribute__((ext_vector_type(8)));
typedef _Float16 f16x4 __attribute__((ext_vector_type(4)));
typedef float    f32x4 __attribute__((ext_vector_type(4)));

#define F16(x) static_cast<_Float16>(x)

#if __has_builtin(__builtin_amdgcn_exp2f)
#define EXP2(x) __builtin_amdgcn_exp2f(x)
#else
#define EXP2(x) exp2f(x)
#endif

// async global->LDS DMA, 16 B per lane; lane i lands at ldsbase + i*16
__device__ __forceinline__ void gl_lds16(const void* g, void* l) {
    __builtin_amdgcn_global_load_lds(
        (const __attribute__((address_space(1))) unsigned int*)g,
        (__attribute__((address_space(3))) unsigned int*)l, 16, 0, 0);
}

// ---------------- prep: weights -> f16 transposed wt[mat][o][d] -------------
__global__ void prep_kernel(const float* __restrict__ wq, const float* __restrict__ wk,
                            const float* __restrict__ wv, _Float16* __restrict__ wt) {
    const int idx = blockIdx.x * 256 + threadIdx.x;   // 196,608 exact
    const int mat = idx >> 16;
    const int r = idx & 65535;
    const int o = r >> 8, d = r & 255;                // d consecutive -> coalesced write
    const float* w = (mat == 0) ? wq : (mat == 1 ? wk : wv);
    wt[(mat << 16) + o * 256 + d] = (_Float16)w[d * 256 + o];
}

// ---------------- pkv: fused maxpool + Q/K/V projections (blob read ONCE) ---
// grid 512 = b(4) x y'(32) x xh(4). Block: 32 blob rows (2 y-rows x 16 x),
// staged f32->f16 in LDS; pooled 8 rows in LDS; 8 waves:
//   waves 0-3: K cols [wid*64,+64);  waves 4-7: V cols [(wid-4)*64,+64);
//   every wave: Q cols [wid*32,+32) from pooled rows (8 valid of 16).
__global__ __launch_bounds__(512, 2) void pkv_kernel(
    const float* __restrict__ blob, const _Float16* __restrict__ wt,
    const float* __restrict__ bq, const float* __restrict__ bk, const float* __restrict__ bv,
    _Float16* __restrict__ qo, _Float16* __restrict__ ko, _Float16* __restrict__ vo) {
    __shared__ _Float16 As[32 * 264];
    __shared__ _Float16 Ps[16 * 264];   // rows 0..7 valid

    const int tid = threadIdx.x;
    const int lane = tid & 63, wid = tid >> 6;
    const int quad = lane >> 4, l16 = lane & 15;
    const int xh = blockIdx.x & 3, yp = (blockIdx.x >> 2) & 31, b = blockIdx.x >> 7;

    // ---- stage 32 rows x 256 f32 -> LDS f16 (coalesced) ----
    {
        const int rloc = tid >> 4;
        const int c0 = (tid & 15) * 4;
        const int yy = rloc >> 4, xx = rloc & 15;
        const float* grow = blob + (size_t)(b * 4096 + (2 * yp + yy) * 64 + xh * 16 + xx) * 256;
#pragma unroll
        for (int it = 0; it < 4; ++it) {
            const int c = c0 + it * 64;
            const float4 f = *(const float4*)(grow + c);
            auto h0 = __builtin_amdgcn_cvt_pkrtz(f.x, f.y);
            auto h1 = __builtin_amdgcn_cvt_pkrtz(f.z, f.w);
            *(f16x4*)&As[rloc * 264 + c] = (f16x4){F16(h0[0]), F16(h0[1]), F16(h1[0]), F16(h1[1])};
        }
    }
    __syncthreads();

    // ---- pool 8 rows (f16 max == f32 max then cvt: monotone, exact) ----
    {
        const int px = tid >> 6, co = (tid & 63) * 4;
        const f16x4 a = *(const f16x4*)&As[(2 * px) * 264 + co];
        const f16x4 b2 = *(const f16x4*)&As[(2 * px + 1) * 264 + co];
        const f16x4 c2 = *(const f16x4*)&As[(16 + 2 * px) * 264 + co];
        const f16x4 d2 = *(const f16x4*)&As[(17 + 2 * px) * 264 + co];
        f16x4 m;
#pragma unroll
        for (int r = 0; r < 4; ++r) {
            _Float16 t1 = a[r] > b2[r] ? a[r] : b2[r];
            _Float16 t2 = c2[r] > d2[r] ? c2[r] : d2[r];
            m[r] = t1 > t2 ? t1 : t2;
        }
        *(f16x4*)&Ps[px * 264 + co] = m;
    }
    __syncthreads();

    // ---- GEMMs ----
    const bool isV = wid >= 4;
    const int colb = (wid & 3) * 64;
    const _Float16* wm = wt + (isV ? 131072 : 65536);

    f32x4 acc[2][4], qacc[2];
#pragma unroll
    for (int mc = 0; mc < 2; ++mc)
#pragma unroll
        for (int nt = 0; nt < 4; ++nt) acc[mc][nt] = (f32x4){0.f, 0.f, 0.f, 0.f};
    qacc[0] = (f32x4){0.f, 0.f, 0.f, 0.f}; qacc[1] = qacc[0];

#pragma unroll
    for (int kc = 0; kc < 8; ++kc) {
        const int ko_ = kc * 32 + quad * 8;
        const f16x8 a0 = *(const f16x8*)&As[l16 * 264 + ko_];
        const f16x8 a1 = *(const f16x8*)&As[(16 + l16) * 264 + ko_];
        const f16x8 aq = *(const f16x8*)&Ps[l16 * 264 + ko_];
#pragma unroll
        for (int nt = 0; nt < 4; ++nt) {
            const f16x8 bf = *(const f16x8*)(wm + (colb + nt * 16 + l16) * 256 + ko_);
            acc[0][nt] = __builtin_amdgcn_mfma_f32_16x16x32_f16(a0, bf, acc[0][nt], 0, 0, 0);
            acc[1][nt] = __builtin_amdgcn_mfma_f32_16x16x32_f16(a1, bf, acc[1][nt], 0, 0, 0);
        }
#pragma unroll
        for (int ntq = 0; ntq < 2; ++ntq) {
            const f16x8 bf = *(const f16x8*)(wt + (wid * 32 + ntq * 16 + l16) * 256 + ko_);
            qacc[ntq] = __builtin_amdgcn_mfma_f32_16x16x32_f16(aq, bf, qacc[ntq], 0, 0, 0);
        }
    }

    // ---- K/V epilogue ----
#pragma unroll
    for (int nt = 0; nt < 4; ++nt) {
        const int o = colb + nt * 16 + l16;
        const int nh = o >> 5, kk = o & 31;
#pragma unroll
        for (int mc = 0; mc < 2; ++mc) {
            const int xx0 = quad * 4;                     // rloc = mc*16+quad*4+r
            const int i0g = (2 * yp + mc) * 64 + xh * 16 + xx0;
            if (!isV) {
                const float bs = bk[o];
#pragma unroll
                for (int r = 0; r < 4; ++r)
                    ko[(((size_t)(b * 8 + nh) * 4096 + i0g + r) << 5) + kk] = (_Float16)(acc[mc][nt][r] + bs);
            } else {
                const float bs = bv[o];
                f16x4 pv;
#pragma unroll
                for (int r = 0; r < 4; ++r) {
                    const float x = acc[mc][nt][r] + bs;
                    const float sg = 1.0f / (1.0f + __expf(-x));
                    pv[r] = (_Float16)(x * sg);
                }
                *(f16x4*)(vo + (((size_t)(b * 8 + nh) * 32 + kk) << 12) + i0g) = pv;
            }
        }
    }
    // ---- Q epilogue (valid pooled rows = 0..7 -> quads 0,1 only) ----
    if (quad < 2) {
#pragma unroll
        for (int ntq = 0; ntq < 2; ++ntq) {
            const int o = wid * 32 + ntq * 16 + l16;
            const int nh = o >> 5, kk = o & 31;
            const float bs = bq[o];
#pragma unroll
            for (int r = 0; r < 4; ++r) {
                const int px = quad * 4 + r;
                const int m = yp * 32 + xh * 8 + px;
                // scale = (1/sqrt(32)) * log2(e): attn uses exp2
                qo[(((b * 8 + nh) * 1024 + m) << 5) + kk] = (_Float16)((qacc[ntq][r] + bs) * 0.25503508f);
            }
        }
    }
}

// ---------------- attn: wave-private streams, drain-free pacing barrier -----
// grid 1024 = 32 bn (XCD swizzle) x 32 mt; 8 waves (512 thr), 32 q-rows/block.
// Wave wid owns keys [wid*512,+512); private double-buffered 32-key tile:
// [K0 1K | K1 1K | V 2K] per buffer, wave region 8 KB, tiles total 64 KB.
// Own-DMA sync: s_waitcnt vmcnt(4) (0 only on last step); raw s_barrier per
// step for cross-block L2 phase-lock (no drain needed - tiles are private).
// K sub-tile swizzle: slot(k,c) = k*4 + ((c+(k>>2))&3) -> conflict-free b128.
// V swizzle (16B granules, DMA-contiguous): L(v,G) = v*4 + ((G+((v>>1)&3))&3)
//   -> read phase hits each slot exactly 2x -> 2-way only (free).
__global__ __launch_bounds__(512, 4) void attn_kernel(
    const _Float16* __restrict__ qb,   // [32][1024][32] (pre-scaled log2e/sqrt32)
    const _Float16* __restrict__ kb,   // [32][4096][32]
    const _Float16* __restrict__ vt,   // [32][32][4096] (V^T)
    float* __restrict__ out) {         // [4][1024][256]
    __shared__ __align__(16) char tiles[65536];     // 8 waves x 2 bufs x 4 KB
    __shared__ float epi[32 * 33 + 32];             // num[32][33] + den[32]

    const int tid = threadIdx.x;
    const int lane = tid & 63, wid = tid >> 6;
    const int quad = lane >> 4, l16 = lane & 15;
    const int bn = blockIdx.x & 31, mt = blockIdx.x >> 5;
    const int b = bn >> 3, n = bn & 7;
    const int m0 = mt * 32;

    for (int i = tid; i < 32 * 33 + 32; i += 512) epi[i] = 0.f;
    __syncthreads();

    // Q fragments: 32 q-rows (2 mc)
    f16x8 qf[2];
#pragma unroll
    for (int mc = 0; mc < 2; ++mc)
        qf[mc] = *(const f16x8*)(qb + (((bn << 10) + m0 + mc * 16 + l16) << 5) + quad * 8);

    // ---- DMA source lane addresses (swizzle inverses) ----
    const int i00 = wid << 9;                       // this wave's key base
    const int kk0 = lane >> 2, ck = ((lane & 3) - (lane >> 4)) & 3;
    const _Float16* ksA = kb + ((size_t)bn << 17) + (i00 + kk0) * 32 + ck * 8;
    const _Float16* ksB = ksA + 16 * 32;            // keys 16..31
    const int vvA = lane >> 2;
    const int GA = ((lane & 3) - ((vvA >> 1) & 3)) & 3;
    const _Float16* vsA = vt + ((size_t)bn << 17) + vvA * 4096 + i00 + GA * 8;
    const int vvB = 16 + vvA;
    const int GB = ((lane & 3) - ((vvB >> 1) & 3)) & 3;
    const _Float16* vsB = vt + ((size_t)bn << 17) + vvB * 4096 + i00 + GB * 8;

    char* wtl = tiles + wid * 8192;
    // prologue: step 0 -> buffer 0
    gl_lds16(ksA, wtl);          gl_lds16(ksB, wtl + 1024);
    gl_lds16(vsA, wtl + 2048);   gl_lds16(vsB, wtl + 3072);
    ksA += 1024; ksB += 1024; vsA += 32; vsB += 32;

    f32x4 acc[2][2];
    acc[0][0] = (f32x4){0.f, 0.f, 0.f, 0.f}; acc[0][1] = acc[0][0];
    acc[1][0] = acc[0][0];                    acc[1][1] = acc[0][0];
    float ps[2] = {0.f, 0.f};

    const int koff = l16 * 64 + ((quad + (l16 >> 2)) & 3) * 16;
    const int vbase = 2048 + l16 * 64 + (quad & 1) * 8;
    const int vrot = (quad >> 1) + ((l16 >> 1) & 3);

#pragma unroll 1
    for (int s = 0; s < 16; ++s) {
        const int bf = (s & 1) << 12;
        if (s < 15) {
            char* nb = wtl + (((s + 1) & 1) << 12);
            gl_lds16(ksA, nb);          gl_lds16(ksB, nb + 1024);
            gl_lds16(vsA, nb + 2048);   gl_lds16(vsB, nb + 3072);
            ksA += 1024; ksB += 1024; vsA += 32; vsB += 32;
            asm volatile("s_waitcnt vmcnt(4)" ::: "memory");
        } else {
            asm volatile("s_waitcnt vmcnt(0)" ::: "memory");
        }
#pragma unroll
        for (int tloc = 0; tloc < 2; ++tloc) {
            const f16x8 kf = *(const f16x8*)(wtl + bf + tloc * 1024 + koff);
            const int sl = ((tloc * 2 + vrot) & 3) * 16;
            const f16x4 va0 = *(const f16x4*)(wtl + bf + vbase + sl);
            const f16x4 va1 = *(const f16x4*)(wtl + bf + vbase + 1024 + sl);
            f16x4 pb[2];
#pragma unroll
            for (int mc = 0; mc < 2; ++mc) {
                f32x4 sc = __builtin_amdgcn_mfma_f32_16x16x32_f16(kf, qf[mc], (f32x4){0.f, 0.f, 0.f, 0.f}, 0, 0, 0);
                const float p0 = EXP2(sc[0]), p1 = EXP2(sc[1]), p2 = EXP2(sc[2]), p3 = EXP2(sc[3]);
                ps[mc] += (p0 + p1) + (p2 + p3);
                auto e0 = __builtin_amdgcn_cvt_pkrtz(p0, p1);
                auto e1 = __builtin_amdgcn_cvt_pkrtz(p2, p3);
                pb[mc] = (f16x4){F16(e0[0]), F16(e0[1]), F16(e1[0]), F16(e1[1])};
            }
#pragma unroll
            for (int mc = 0; mc < 2; ++mc) {
                acc[mc][0] = __builtin_amdgcn_mfma_f32_16x16x16f16(va0, pb[mc], acc[mc][0], 0, 0, 0);
                acc[mc][1] = __builtin_amdgcn_mfma_f32_16x16x16f16(va1, pb[mc], acc[mc][1], 0, 0, 0);
            }
        }
        // pacing barrier (no drain): keeps the block's waves step-aligned so
        // co-resident same-bn blocks stream the same K/V window through L2
        asm volatile("s_barrier" ::: "memory");
    }

    // ---- epilogue: 8-way key-split combine ----
    float* num = epi;            // [32][33]
    float* den = epi + 32 * 33;  // [32]
#pragma unroll
    for (int mc = 0; mc < 2; ++mc) {
        ps[mc] += __shfl_xor(ps[mc], 16);
        ps[mc] += __shfl_xor(ps[mc], 32);
    }
#pragma unroll
    for (int mc = 0; mc < 2; ++mc)
#pragma unroll
        for (int vc = 0; vc < 2; ++vc)
#pragma unroll
            for (int r = 0; r < 4; ++r)
                atomicAdd(&num[(mc * 16 + l16) * 33 + vc * 16 + quad * 4 + r], acc[mc][vc][r]);
    if (quad == 0) {
#pragma unroll
        for (int mc = 0; mc < 2; ++mc) atomicAdd(&den[mc * 16 + l16], ps[mc]);
    }
    __syncthreads();

    // store: 32 m x 32 v = 1024 f32 = 256 threads x one float4
    if (tid < 256) {
        const int mloc = tid >> 3, v4 = (tid & 7) * 4;
        const float inv = 1.0f / den[mloc];
        const float* nr = num + mloc * 33 + v4;
        float4 o = {nr[0] * inv, nr[1] * inv, nr[2] * inv, nr[3] * inv};
        *(float4*)(out + (((b << 10) + m0 + mloc) << 8) + n * 32 + v4) = o;
    }
}

// ---------------- launch -----------------------------------------------------
extern "C" void kernel_launch(void* const* d_in, const int* in_sizes, int n_in,
                              void* d_out, int out_size, void* d_ws, size_t ws_size,
                              hipStream_t stream) {
    const float* blob = (const float*)d_in[0];
    const float* wq = (const float*)d_in[1];
    const float* bq = (const float*)d_in[2];
    const float* wk = (const float*)d_in[3];
    const float* bk = (const float*)d_in[4];
    const float* wv = (const float*)d_in[5];
    const float* bv = (const float*)d_in[6];
    float* out = (float*)d_out;

    char* ws = (char*)d_ws;
    _Float16* wt = (_Float16*)(ws);                    //   393,216 B  [Q|K|V]
    _Float16* ko = (_Float16*)(ws + 393216);           // 8,388,608 B
    _Float16* vo = (_Float16*)(ws + 8781824);          // 8,388,608 B
    _Float16* qo = (_Float16*)(ws + 17170432);         // 2,097,152 B

    prep_kernel<<<768, 256, 0, stream>>>(wq, wk, wv, wt);
    pkv_kernel<<<512, 512, 0, stream>>>(blob, wt, bq, bk, bv, qo, ko, vo);
    attn_kernel<<<1024, 512, 0, stream>>>(qo, ko, vo, out);
}

// Round 11
// 173.730 us; speedup vs baseline: 1.0408x; 1.0408x over previous
//
#include <hip/hip_runtime.h>

// B=4, H=W=64, D=256, N=8, K=V=32, H2=W2=32, HW=4096, M=1024 pooled/batch.

typedef _Float16 f16x8 __attribute__((ext_vector_type(8)));
typedef _Float16 f16x4 __attribute__((ext_vector_type(4)));
typedef float    f32x4 __attribute__((ext_vector_type(4)));

#define F16(x) static_cast<_Float16>(x)

#if __has_builtin(__builtin_amdgcn_exp2f)
#define EXP2(x) __builtin_amdgcn_exp2f(x)
#else
#define EXP2(x) exp2f(x)
#endif

// async global->LDS DMA, 16 B per lane; lane i lands at ldsbase + i*16
__device__ __forceinline__ void gl_lds16(const void* g, void* l) {
    __builtin_amdgcn_global_load_lds(
        (const __attribute__((address_space(1))) unsigned int*)g,
        (__attribute__((address_space(3))) unsigned int*)l, 16, 0, 0);
}

// ---------------- prep: weights -> f16 transposed wt[mat][o][d] -------------
__global__ void prep_kernel(const float* __restrict__ wq, const float* __restrict__ wk,
                            const float* __restrict__ wv, _Float16* __restrict__ wt) {
    const int idx = blockIdx.x * 256 + threadIdx.x;   // 196,608 exact
    const int mat = idx >> 16;
    const int r = idx & 65535;
    const int o = r >> 8, d = r & 255;                // d consecutive -> coalesced write
    const float* w = (mat == 0) ? wq : (mat == 1 ? wk : wv);
    wt[(mat << 16) + o * 256 + d] = (_Float16)w[d * 256 + o];
}

// ---------------- pkv: fused maxpool + Q/K/V projections (blob read ONCE) ---
// grid 512 = b(4) x y'(32) x xh(4). Block: 32 blob rows (2 y-rows x 16 x),
// staged f32->f16 in LDS; pooled 8 rows in LDS; 8 waves:
//   waves 0-3: K cols [wid*64,+64);  waves 4-7: V cols [(wid-4)*64,+64);
//   every wave: Q cols [wid*32,+32) from pooled rows (8 valid of 16).
__global__ __launch_bounds__(512, 2) void pkv_kernel(
    const float* __restrict__ blob, const _Float16* __restrict__ wt,
    const float* __restrict__ bq, const float* __restrict__ bk, const float* __restrict__ bv,
    _Float16* __restrict__ qo, _Float16* __restrict__ ko, _Float16* __restrict__ vo) {
    __shared__ _Float16 As[32 * 264];
    __shared__ _Float16 Ps[16 * 264];   // rows 0..7 valid

    const int tid = threadIdx.x;
    const int lane = tid & 63, wid = tid >> 6;
    const int quad = lane >> 4, l16 = lane & 15;
    const int xh = blockIdx.x & 3, yp = (blockIdx.x >> 2) & 31, b = blockIdx.x >> 7;

    // ---- stage 32 rows x 256 f32 -> LDS f16 (coalesced) ----
    {
        const int rloc = tid >> 4;
        const int c0 = (tid & 15) * 4;
        const int yy = rloc >> 4, xx = rloc & 15;
        const float* grow = blob + (size_t)(b * 4096 + (2 * yp + yy) * 64 + xh * 16 + xx) * 256;
#pragma unroll
        for (int it = 0; it < 4; ++it) {
            const int c = c0 + it * 64;
            const float4 f = *(const float4*)(grow + c);
            auto h0 = __builtin_amdgcn_cvt_pkrtz(f.x, f.y);
            auto h1 = __builtin_amdgcn_cvt_pkrtz(f.z, f.w);
            *(f16x4*)&As[rloc * 264 + c] = (f16x4){F16(h0[0]), F16(h0[1]), F16(h1[0]), F16(h1[1])};
        }
    }
    __syncthreads();

    // ---- pool 8 rows (f16 max == f32 max then cvt: monotone, exact) ----
    {
        const int px = tid >> 6, co = (tid & 63) * 4;
        const f16x4 a = *(const f16x4*)&As[(2 * px) * 264 + co];
        const f16x4 b2 = *(const f16x4*)&As[(2 * px + 1) * 264 + co];
        const f16x4 c2 = *(const f16x4*)&As[(16 + 2 * px) * 264 + co];
        const f16x4 d2 = *(const f16x4*)&As[(17 + 2 * px) * 264 + co];
        f16x4 m;
#pragma unroll
        for (int r = 0; r < 4; ++r) {
            _Float16 t1 = a[r] > b2[r] ? a[r] : b2[r];
            _Float16 t2 = c2[r] > d2[r] ? c2[r] : d2[r];
            m[r] = t1 > t2 ? t1 : t2;
        }
        *(f16x4*)&Ps[px * 264 + co] = m;
    }
    __syncthreads();

    // ---- GEMMs ----
    const bool isV = wid >= 4;
    const int colb = (wid & 3) * 64;
    const _Float16* wm = wt + (isV ? 131072 : 65536);

    f32x4 acc[2][4], qacc[2];
#pragma unroll
    for (int mc = 0; mc < 2; ++mc)
#pragma unroll
        for (int nt = 0; nt < 4; ++nt) acc[mc][nt] = (f32x4){0.f, 0.f, 0.f, 0.f};
    qacc[0] = (f32x4){0.f, 0.f, 0.f, 0.f}; qacc[1] = qacc[0];

#pragma unroll
    for (int kc = 0; kc < 8; ++kc) {
        const int ko_ = kc * 32 + quad * 8;
        const f16x8 a0 = *(const f16x8*)&As[l16 * 264 + ko_];
        const f16x8 a1 = *(const f16x8*)&As[(16 + l16) * 264 + ko_];
        const f16x8 aq = *(const f16x8*)&Ps[l16 * 264 + ko_];
#pragma unroll
        for (int nt = 0; nt < 4; ++nt) {
            const f16x8 bf = *(const f16x8*)(wm + (colb + nt * 16 + l16) * 256 + ko_);
            acc[0][nt] = __builtin_amdgcn_mfma_f32_16x16x32_f16(a0, bf, acc[0][nt], 0, 0, 0);
            acc[1][nt] = __builtin_amdgcn_mfma_f32_16x16x32_f16(a1, bf, acc[1][nt], 0, 0, 0);
        }
#pragma unroll
        for (int ntq = 0; ntq < 2; ++ntq) {
            const f16x8 bf = *(const f16x8*)(wt + (wid * 32 + ntq * 16 + l16) * 256 + ko_);
            qacc[ntq] = __builtin_amdgcn_mfma_f32_16x16x32_f16(aq, bf, qacc[ntq], 0, 0, 0);
        }
    }

    // ---- K/V epilogue ----
#pragma unroll
    for (int nt = 0; nt < 4; ++nt) {
        const int o = colb + nt * 16 + l16;
        const int nh = o >> 5, kk = o & 31;
#pragma unroll
        for (int mc = 0; mc < 2; ++mc) {
            const int xx0 = quad * 4;                     // rloc = mc*16+quad*4+r
            const int i0g = (2 * yp + mc) * 64 + xh * 16 + xx0;
            if (!isV) {
                const float bs = bk[o];
#pragma unroll
                for (int r = 0; r < 4; ++r)
                    ko[(((size_t)(b * 8 + nh) * 4096 + i0g + r) << 5) + kk] = (_Float16)(acc[mc][nt][r] + bs);
            } else {
                const float bs = bv[o];
                f16x4 pv;
#pragma unroll
                for (int r = 0; r < 4; ++r) {
                    const float x = acc[mc][nt][r] + bs;
                    const float sg = 1.0f / (1.0f + __expf(-x));
                    pv[r] = (_Float16)(x * sg);
                }
                *(f16x4*)(vo + (((size_t)(b * 8 + nh) * 32 + kk) << 12) + i0g) = pv;
            }
        }
    }
    // ---- Q epilogue (valid pooled rows = 0..7 -> quads 0,1 only) ----
    if (quad < 2) {
#pragma unroll
        for (int ntq = 0; ntq < 2; ++ntq) {
            const int o = wid * 32 + ntq * 16 + l16;
            const int nh = o >> 5, kk = o & 31;
            const float bs = bq[o];
#pragma unroll
            for (int r = 0; r < 4; ++r) {
                const int px = quad * 4 + r;
                const int m = yp * 32 + xh * 8 + px;
                // scale = (1/sqrt(32)) * log2(e): attn uses exp2
                qo[(((b * 8 + nh) * 1024 + m) << 5) + kk] = (_Float16)((qacc[ntq][r] + bs) * 0.25503508f);
            }
        }
    }
}

// ---------------- attn: 64 shared q-rows, wave-private streams, vmcnt(4) ----
// grid 512 = 32 bn (XCD swizzle) x 16 mt; 8 waves (512 thr); ALL waves hold
// the block's 64 q-rows (qf[4]); wave wid owns keys [wid*512,+512) with a
// private double-buffered 32-key tile [K0 1K|K1 1K|V0 1K|V1 1K] (8 KB/wave).
// Own-DMA sync: s_waitcnt vmcnt(4) (true double-buffer; 0 only on last step);
// raw s_barrier per step for cross-block L2 phase-lock (no drain: private).
// K swizzle slot(k,c) = k*4 + ((c+(k>>2))&3) -> conflict-free b128 reads.
// V swizzle (16B granules) L(v,G) = v*4 + ((G+((v>>1)&3))&3) -> 2-way b64
// reads (free). Denominator on VALU (ones-MFMA regressed in R9: it extends
// the serial MFMA chain by a third). SQ_LDS_BANK_CONFLICT ~3.1M is the
// global_load_lds write-path floor - not actionable (R6/R7/R10 invariant).
__global__ __launch_bounds__(512, 4) void attn_kernel(
    const _Float16* __restrict__ qb,   // [32][1024][32] (pre-scaled log2e/sqrt32)
    const _Float16* __restrict__ kb,   // [32][4096][32]
    const _Float16* __restrict__ vt,   // [32][32][4096] (V^T)
    float* __restrict__ out) {         // [4][1024][256]
    __shared__ __align__(16) char tiles[65536];     // 8 waves x 2 bufs x 4 KB
    __shared__ float epi[64 * 33 + 64];             // num[64][33] + den[64]

    const int tid = threadIdx.x;
    const int lane = tid & 63, wid = tid >> 6;
    const int quad = lane >> 4, l16 = lane & 15;
    const int bn = blockIdx.x & 31, mt = blockIdx.x >> 5;
    const int b = bn >> 3, n = bn & 7;
    const int m0 = mt * 64;

    for (int i = tid; i < 64 * 33 + 64; i += 512) epi[i] = 0.f;
    __syncthreads();

    // Q fragments: all 64 block q-rows per wave
    f16x8 qf[4];
#pragma unroll
    for (int mc = 0; mc < 4; ++mc)
        qf[mc] = *(const f16x8*)(qb + (((bn << 10) + m0 + mc * 16 + l16) << 5) + quad * 8);

    // ---- DMA source lane addresses (swizzle inverses) ----
    const int i00 = wid << 9;                       // this wave's key base
    const int kk0 = lane >> 2, ck = ((lane & 3) - (lane >> 4)) & 3;
    const _Float16* ksA = kb + ((size_t)bn << 17) + (i00 + kk0) * 32 + ck * 8;
    const _Float16* ksB = ksA + 512;                // keys +16
    const int vvA = lane >> 2;
    const int GA = ((lane & 3) - ((vvA >> 1) & 3)) & 3;
    const _Float16* vsA = vt + ((size_t)bn << 17) + vvA * 4096 + i00 + GA * 8;
    const _Float16* vsB = vsA + 16 * 4096;          // v rows 16..31 (same G rot)

    char* wtl = tiles + wid * 8192;
    // prologue: step 0 -> buffer 0
    gl_lds16(ksA, wtl);          gl_lds16(ksB, wtl + 1024);
    gl_lds16(vsA, wtl + 2048);   gl_lds16(vsB, wtl + 3072);
    ksA += 1024; ksB += 1024; vsA += 32; vsB += 32;

    f32x4 acc[4][2];   // [mc][vc]: out^T[v=vc*16+quad*4+r][m=mc*16+l16]
#pragma unroll
    for (int mc = 0; mc < 4; ++mc) { acc[mc][0] = (f32x4){0.f, 0.f, 0.f, 0.f}; acc[mc][1] = acc[mc][0]; }
    float ps[4] = {0.f, 0.f, 0.f, 0.f};

    const int koff = l16 * 64 + ((quad + (l16 >> 2)) & 3) * 16;
    const int vbase = 2048 + l16 * 64 + (quad & 1) * 8;
    const int vrot = (quad >> 1) + ((l16 >> 1) & 3);

#pragma unroll 1
    for (int s = 0; s < 16; ++s) {
        const int bf = (s & 1) << 12;
        if (s < 15) {
            char* nb = wtl + (((s + 1) & 1) << 12);
            gl_lds16(ksA, nb);          gl_lds16(ksB, nb + 1024);
            gl_lds16(vsA, nb + 2048);   gl_lds16(vsB, nb + 3072);
            ksA += 1024; ksB += 1024; vsA += 32; vsB += 32;
            asm volatile("s_waitcnt vmcnt(4)" ::: "memory");   // current buf done
        } else {
            asm volatile("s_waitcnt vmcnt(0)" ::: "memory");
        }
#pragma unroll
        for (int tloc = 0; tloc < 2; ++tloc) {
            const f16x8 kf = *(const f16x8*)(wtl + bf + tloc * 1024 + koff);
            const int sl = ((tloc * 2 + vrot) & 3) * 16;
            const f16x4 va0 = *(const f16x4*)(wtl + bf + vbase + sl);
            const f16x4 va1 = *(const f16x4*)(wtl + bf + 1024 + vbase + sl);
            f16x4 pb[4];
#pragma unroll
            for (int mc = 0; mc < 4; ++mc) {
                f32x4 sc = __builtin_amdgcn_mfma_f32_16x16x32_f16(kf, qf[mc], (f32x4){0.f, 0.f, 0.f, 0.f}, 0, 0, 0);
                const float p0 = EXP2(sc[0]), p1 = EXP2(sc[1]), p2 = EXP2(sc[2]), p3 = EXP2(sc[3]);
                ps[mc] += (p0 + p1) + (p2 + p3);
                auto e0 = __builtin_amdgcn_cvt_pkrtz(p0, p1);
                auto e1 = __builtin_amdgcn_cvt_pkrtz(p2, p3);
                pb[mc] = (f16x4){F16(e0[0]), F16(e0[1]), F16(e1[0]), F16(e1[1])};
            }
#pragma unroll
            for (int mc = 0; mc < 4; ++mc) {
                acc[mc][0] = __builtin_amdgcn_mfma_f32_16x16x16f16(va0, pb[mc], acc[mc][0], 0, 0, 0);
                acc[mc][1] = __builtin_amdgcn_mfma_f32_16x16x16f16(va1, pb[mc], acc[mc][1], 0, 0, 0);
            }
        }
        // pacing barrier (no drain): keeps the block's waves step-aligned so
        // co-resident same-bn blocks stream the same K/V window through L2
        asm volatile("s_barrier" ::: "memory");
    }

    // ---- epilogue: 8-way key-split combine ----
    float* num = epi;            // [64][33]
    float* den = epi + 64 * 33;  // [64]
#pragma unroll
    for (int mc = 0; mc < 4; ++mc) {
        ps[mc] += __shfl_xor(ps[mc], 16);
        ps[mc] += __shfl_xor(ps[mc], 32);
    }
#pragma unroll
    for (int mc = 0; mc < 4; ++mc)
#pragma unroll
        for (int vc = 0; vc < 2; ++vc)
#pragma unroll
            for (int r = 0; r < 4; ++r)
                atomicAdd(&num[(mc * 16 + l16) * 33 + vc * 16 + quad * 4 + r], acc[mc][vc][r]);
    if (quad == 0) {
#pragma unroll
        for (int mc = 0; mc < 4; ++mc) atomicAdd(&den[mc * 16 + l16], ps[mc]);
    }
    __syncthreads();

    // store: 64 m x 32 v = 2048 f32 = 512 threads x one float4
    {
        const int mloc = tid >> 3, v4 = (tid & 7) * 4;
        const float inv = 1.0f / den[mloc];
        const float* nr = num + mloc * 33 + v4;
        float4 o = {nr[0] * inv, nr[1] * inv, nr[2] * inv, nr[3] * inv};
        *(float4*)(out + (((b << 10) + m0 + mloc) << 8) + n * 32 + v4) = o;
    }
}

// ---------------- launch -----------------------------------------------------
extern "C" void kernel_launch(void* const* d_in, const int* in_sizes, int n_in,
                              void* d_out, int out_size, void* d_ws, size_t ws_size,
                              hipStream_t stream) {
    const float* blob = (const float*)d_in[0];
    const float* wq = (const float*)d_in[1];
    const float* bq = (const float*)d_in[2];
    const float* wk = (const float*)d_in[3];
    const float* bk = (const float*)d_in[4];
    const float* wv = (const float*)d_in[5];
    const float* bv = (const float*)d_in[6];
    float* out = (float*)d_out;

    char* ws = (char*)d_ws;
    _Float16* wt = (_Float16*)(ws);                    //   393,216 B  [Q|K|V]
    _Float16* ko = (_Float16*)(ws + 393216);           // 8,388,608 B
    _Float16* vo = (_Float16*)(ws + 8781824);          // 8,388,608 B
    _Float16* qo = (_Float16*)(ws + 17170432);         // 2,097,152 B

    prep_kernel<<<768, 256, 0, stream>>>(wq, wk, wv, wt);
    pkv_kernel<<<512, 512, 0, stream>>>(blob, wt, bq, bk, bv, qo, ko, vo);
    attn_kernel<<<512, 512, 0, stream>>>(qo, ko, vo, out);
}